// Round 2
// baseline (112801.526 us; speedup 1.0000x reference)
//
#include <hip/hip_runtime.h>
#include <hip/hip_bf16.h>

// Problem constants
#define B    16
#define TIN  400
#define TT   100
#define EMBD 128
#define EHD  256
#define VV   32000
#define NV   31998
// tokens: UNK=0, START=1, END=2, PAD=3

__device__ __forceinline__ float sigf(float x) { return 1.f / (1.f + __expf(-x)); }
__device__ __forceinline__ float fast_tanh(float x) {
    float e = __expf(2.f * x);
    return 1.f - 2.f / (e + 1.f);
}

// ---- flag barrier helpers (slots stride 16 ints = 64B/line) ----
__device__ __forceinline__ void slot_wait(int* sl, int n, int tid) {
    if (tid < n) {
        while (__hip_atomic_load(&sl[tid * 16], __ATOMIC_ACQUIRE, __HIP_MEMORY_SCOPE_AGENT) == 0)
            __builtin_amdgcn_s_sleep(1);
    }
    __syncthreads();
}
__device__ __forceinline__ void slot_signal(int* sl, int idx) {
    __syncthreads();
    if (threadIdx.x == 0)
        __hip_atomic_store(&sl[idx * 16], 1, __ATOMIC_RELEASE, __HIP_MEMORY_SCOPE_AGENT);
}

// ---------------------------------------------------------------- zero
__global__ __launch_bounds__(256) void k_zero(float* __restrict__ p, int n) {
    int i = blockIdx.x * 256 + threadIdx.x;
    if (i < n) p[i] = 0.f;
}

// ------------------------------------------------ encoder input GEMM L0
__global__ __launch_bounds__(256) void k_gx0(const int* __restrict__ ids, const float* __restrict__ emb,
                                             const float* __restrict__ Wih, const float* __restrict__ bias,
                                             float* __restrict__ gx) {
    int blk = blockIdx.x, dir = blk / TIN, t = blk % TIN;
    __shared__ float se[16][132];
    int tid = threadIdx.x;
    for (int i = tid; i < 16 * 128; i += 256) {
        int b = i >> 7, k = i & 127;
        int id = ids[b * TIN + t];
        if ((unsigned)id >= VV) id = 0;
        se[b][k] = emb[(size_t)id * EMBD + k];
    }
    __syncthreads();
    const float* W = Wih + (size_t)dir * 1024 * EMBD;
    const float* bb = bias + (size_t)dir * 1024;
    float* out = gx + ((size_t)dir * TIN + t) * (B * 1024);
    for (int c = tid; c < 1024; c += 256) {
        float acc[16];
#pragma unroll
        for (int b = 0; b < 16; b++) acc[b] = 0.f;
        const float4* wr = (const float4*)(W + (size_t)c * EMBD);
        for (int k4 = 0; k4 < 32; k4++) {
            float4 w = wr[k4];
            int k = k4 * 4;
#pragma unroll
            for (int b = 0; b < 16; b++)
                acc[b] += w.x * se[b][k] + w.y * se[b][k + 1] + w.z * se[b][k + 2] + w.w * se[b][k + 3];
        }
        float bv = bb[c];
#pragma unroll
        for (int b = 0; b < 16; b++) out[(size_t)b * 1024 + c] = acc[b] + bv;
    }
}

// ------------------------------------------------ encoder input GEMM L1
__global__ __launch_bounds__(256) void k_gx1(const float* __restrict__ hseq, const float* __restrict__ Wih,
                                             const float* __restrict__ bias, float* __restrict__ gx) {
    int blk = blockIdx.x, dir = blk / TIN, t = blk % TIN;
    __shared__ float sx[16][516];
    int tid = threadIdx.x;
    for (int i = tid; i < 16 * 512; i += 256) sx[i >> 9][i & 511] = hseq[(size_t)t * B * 512 + i];
    __syncthreads();
    const float* W = Wih + (size_t)dir * 1024 * 512;
    const float* bb = bias + (size_t)dir * 1024;
    float* out = gx + ((size_t)dir * TIN + t) * (B * 1024);
    for (int c = tid; c < 1024; c += 256) {
        float acc[16];
#pragma unroll
        for (int b = 0; b < 16; b++) acc[b] = 0.f;
        const float4* wr = (const float4*)(W + (size_t)c * 512);
        for (int k4 = 0; k4 < 128; k4++) {
            float4 w = wr[k4];
            int k = k4 * 4;
#pragma unroll
            for (int b = 0; b < 16; b++)
                acc[b] += w.x * sx[b][k] + w.y * sx[b][k + 1] + w.z * sx[b][k + 2] + w.w * sx[b][k + 3];
        }
        float bv = bb[c];
#pragma unroll
        for (int b = 0; b < 16; b++) out[(size_t)b * 1024 + c] = acc[b] + bv;
    }
}

// ------------------------------------------------ persistent encoder layer
// grid 32 = dir(2) x ublk(16). 256 thr = rowpair(32) x kslice q(8).
// Per block: 16 units x 4 gates = 64 rows; weights in VGPRs for all 400 steps.
// h exchange via global hbuf [par][dir][b][256]; per-dir flag barrier per step.
__global__ __launch_bounds__(256) void k_enc_layer(const float* __restrict__ gx, const float* __restrict__ Whh,
                                                   float* __restrict__ hbuf, float* __restrict__ hout,
                                                   float* __restrict__ hTs, float* __restrict__ cTs,
                                                   int* __restrict__ slots, int layer) {
    int blk = blockIdx.x;
    int dir = blk >> 4;
    int ublk = blk & 15;
    int tid = threadIdx.x;
    int rp = tid >> 3, q = tid & 7;
    int lr0 = rp * 2, lr1 = lr0 + 1;
    int g0 = lr0 & 3, g1 = lr1 & 3;
    int unit0 = ublk * 16 + (lr0 >> 2);
    int unit1 = ublk * 16 + (lr1 >> 2);
    const float* Wd = Whh + (size_t)dir * 1024 * 256;
    float wreg[64];
    {
        const float* r0 = Wd + (size_t)(g0 * 256 + unit0) * 256 + q * 32;
        const float* r1 = Wd + (size_t)(g1 * 256 + unit1) * 256 + q * 32;
#pragma unroll
        for (int e = 0; e < 32; e++) { wreg[e] = r0[e]; wreg[32 + e] = r1[e]; }
    }
    int ub = tid >> 4, bb = tid & 15;   // update role: unit_loc, batch
    float creg = 0.f;
    __shared__ float sh[16 * 288];      // [b][q8][36] swizzled h stage
    __shared__ float sums[32 * 17];     // [row 32][b 16] padded... rows=64 -> [64? ] use lr*17 (lr<64)
    __shared__ float sums2[32 * 17];    // second half (lr 32..63)
    int* dirslots = slots + (size_t)dir * TIN * 16 * 16;

    for (int s = 0; s < TIN; s++) {
        int t = dir ? (TIN - 1 - s) : s;
        int par = s & 1;
        // stage h_prev -> LDS (swizzled)
        const float4* hp = (const float4*)(hbuf + ((size_t)par * 2 + dir) * B * 256);
        for (int i = tid; i < 1024; i += 256) {
            float4 v = hp[i];
            int b = i >> 6, k = (i & 63) * 4;
            *(float4*)&sh[b * 288 + (k >> 5) * 36 + (k & 31)] = v;
        }
        __syncthreads();
        float pa0[16], pa1[16];
        for (int b = 0; b < 16; b++) {
            const float4* hv = (const float4*)&sh[b * 288 + q * 36];
            float a0 = 0.f, a1 = 0.f;
#pragma unroll
            for (int j = 0; j < 8; j++) {
                float4 h4 = hv[j];
                a0 += wreg[4 * j] * h4.x + wreg[4 * j + 1] * h4.y + wreg[4 * j + 2] * h4.z + wreg[4 * j + 3] * h4.w;
                a1 += wreg[32 + 4 * j] * h4.x + wreg[33 + 4 * j] * h4.y + wreg[34 + 4 * j] * h4.z + wreg[35 + 4 * j] * h4.w;
            }
            pa0[b] = a0; pa1[b] = a1;
        }
#pragma unroll
        for (int m = 1; m < 8; m <<= 1) {
#pragma unroll
            for (int b = 0; b < 16; b++) {
                pa0[b] += __shfl_xor(pa0[b], m, 64);
                pa1[b] += __shfl_xor(pa1[b], m, 64);
            }
        }
        if (q == 0) {
            float* s0 = (lr0 < 32) ? sums : sums2;
            float* s1 = (lr1 < 32) ? sums : sums2;
            int l0 = lr0 & 31, l1 = lr1 & 31;
#pragma unroll
            for (int b = 0; b < 16; b++) { s0[l0 * 17 + b] = pa0[b]; s1[l1 * 17 + b] = pa1[b]; }
        }
        __syncthreads();
        // update: all 256 threads: (unit_loc ub, batch bb)
        {
            int unit = ublk * 16 + ub;
            const float* gp = gx + (((size_t)dir * TIN + t) * B + bb) * 1024;
            int lri = ub * 4;
            float ai = ((lri + 0 < 32) ? sums[(lri + 0) * 17 + bb] : sums2[((lri + 0) & 31) * 17 + bb]) + gp[0 * 256 + unit];
            float af = ((lri + 1 < 32) ? sums[(lri + 1) * 17 + bb] : sums2[((lri + 1) & 31) * 17 + bb]) + gp[1 * 256 + unit];
            float ag = ((lri + 2 < 32) ? sums[(lri + 2) * 17 + bb] : sums2[((lri + 2) & 31) * 17 + bb]) + gp[2 * 256 + unit];
            float ao = ((lri + 3 < 32) ? sums[(lri + 3) * 17 + bb] : sums2[((lri + 3) & 31) * 17 + bb]) + gp[3 * 256 + unit];
            float c = sigf(af) * creg + sigf(ai) * fast_tanh(ag);
            float h = sigf(ao) * fast_tanh(c);
            creg = c;
            hbuf[((size_t)(par ^ 1) * 2 + dir) * B * 256 + (size_t)bb * 256 + unit] = h;
            if (layer == 0) hout[((size_t)t * B + bb) * 512 + dir * 256 + unit] = h;
            else            hout[((size_t)bb * TIN + t) * 512 + dir * 256 + unit] = h;
            if (s == TIN - 1) {
                hTs[((size_t)layer * B + bb) * 512 + dir * 256 + unit] = h;
                cTs[((size_t)layer * B + bb) * 512 + dir * 256 + unit] = c;
            }
        }
        // per-dir barrier (16 blocks)
        int* sl = dirslots + (size_t)s * 16 * 16;
        slot_signal(sl, ublk);
        slot_wait(sl, 16, tid);
    }
}

// ------------------------------------------------ enc_attn precompute
__global__ __launch_bounds__(256) void k_encattn(const float* __restrict__ encs, const float* __restrict__ Wea,
                                                 const float* __restrict__ bea, float* __restrict__ encat) {
    int blk = blockIdx.x;
    __shared__ float sx[512];
    int tid = threadIdx.x;
    const float* row = encs + (size_t)blk * 512;
    for (int i = tid; i < 512; i += 256) sx[i] = row[i];
    __syncthreads();
    float a = bea[tid];
    const float4* wr = (const float4*)(Wea + (size_t)tid * 512);
    const float4* xr = (const float4*)sx;
    for (int k4 = 0; k4 < 128; k4++) {
        float4 w = wr[k4], x = xr[k4];
        a += w.x * x.x + w.y * x.y + w.z * x.z + w.w * x.w;
    }
    encat[(size_t)blk * 256 + tid] = a;
}

// ------------------------------------------------ decoder init
__global__ __launch_bounds__(256) void k_dec_init(const float* __restrict__ hTs, const float* __restrict__ cTs,
                                                  const float* __restrict__ Wh, const float* __restrict__ bh,
                                                  const float* __restrict__ Wc, const float* __restrict__ bc,
                                                  float* __restrict__ h0buf, float* __restrict__ c0,
                                                  float* __restrict__ h1buf, float* __restrict__ c1) {
    int idx = blockIdx.x * 256 + threadIdx.x;
    int l = idx >> 12, b = (idx >> 8) & 15, d = idx & 255;
    const float4* h4 = (const float4*)(hTs + ((size_t)l * B + b) * 512);
    const float4* c4 = (const float4*)(cTs + ((size_t)l * B + b) * 512);
    const float4* wh4 = (const float4*)(Wh + (size_t)d * 512);
    const float4* wc4 = (const float4*)(Wc + (size_t)d * 512);
    float ah = bh[d], ac = bc[d];
    for (int k4 = 0; k4 < 128; k4++) {
        float4 w = wh4[k4], x = h4[k4];
        ah += w.x * x.x + w.y * x.y + w.z * x.z + w.w * x.w;
        w = wc4[k4]; x = c4[k4];
        ac += w.x * x.x + w.y * x.y + w.z * x.z + w.w * x.w;
    }
    if (l == 0) { h0buf[(size_t)b * 256 + d] = ah; c0[(size_t)b * 256 + d] = ac; }
    else        { h1buf[(size_t)b * 256 + d] = ah; c1[(size_t)b * 256 + d] = ac; }
}

// ------------------------------------------------ persistent decoder (all 100 steps)
// roles: A cell0 blk 0-31 | B cell1 32-63 | C attn 64-79 | D ctx 80-143
//        E fc1 144-175 | F vocab all | G final blk 255
#define DSTEP 6928
#define SA_O 0
#define SB_O 512
#define SC_O 1024
#define SD_O 1280
#define SE_O 2304
#define SFo_O 2816
#define SG_O 6912

__global__ __launch_bounds__(256) void k_decoder(
    const int* __restrict__ ids, const int* __restrict__ tgt, const int* __restrict__ tlen,
    const float* __restrict__ emb,
    const float* __restrict__ dWih0, const float* __restrict__ dWhh0, const float* __restrict__ db0,
    const float* __restrict__ dWih1, const float* __restrict__ dWhh1, const float* __restrict__ db1,
    const float* __restrict__ Wda, const float* __restrict__ wcov, const float* __restrict__ vat,
    const float* __restrict__ Wv1, const float* __restrict__ bv1,
    const float* __restrict__ Wv2, const float* __restrict__ bv2,
    const float* __restrict__ wctx, const float* __restrict__ bctx,
    const float* __restrict__ wdec, const float* __restrict__ wemb,
    const float* __restrict__ ENCS, const float* __restrict__ ENCAT,
    float* __restrict__ ATT, float* __restrict__ COVG, float* __restrict__ COVL,
    float* __restrict__ CTX, float* __restrict__ FC1,
    float* __restrict__ PCOPY, float* __restrict__ VPART, float* __restrict__ LTGT,
    float* __restrict__ H0, float* __restrict__ C0, float* __restrict__ H1, float* __restrict__ C1,
    int* __restrict__ DSL, float* __restrict__ out)
{
    __shared__ float smem[12400];
    int blk = blockIdx.x, tid = threadIdx.x;
    float wreg[64];
    float creg = 0.f;
    float nllreg = 0.f;

    // per-role persistent weight load
    if (blk < 32) {
        int rp = tid >> 4, q = tid & 15;
        int lr0 = rp * 2, lr1 = lr0 + 1;
        int g0 = lr0 & 3, g1 = lr1 & 3;
        int un0 = blk * 8 + (lr0 >> 2), un1 = blk * 8 + (lr1 >> 2);
#pragma unroll
        for (int e = 0; e < 24; e++) {
            int k = q * 24 + e;
            wreg[e]      = (k < 128) ? dWih0[(size_t)(g0 * 256 + un0) * 128 + k] : dWhh0[(size_t)(g0 * 256 + un0) * 256 + k - 128];
            wreg[24 + e] = (k < 128) ? dWih0[(size_t)(g1 * 256 + un1) * 128 + k] : dWhh0[(size_t)(g1 * 256 + un1) * 256 + k - 128];
        }
        if (tid < 128) creg = C0[(size_t)(tid & 15) * 256 + blk * 8 + (tid >> 4)];
    } else if (blk < 64) {
        int bb = blk - 32;
        int rp = tid >> 4, q = tid & 15;
        int lr0 = rp * 2, lr1 = lr0 + 1;
        int g0 = lr0 & 3, g1 = lr1 & 3;
        int un0 = bb * 8 + (lr0 >> 2), un1 = bb * 8 + (lr1 >> 2);
#pragma unroll
        for (int e = 0; e < 32; e++) {
            int k = q * 32 + e;
            wreg[e]      = (k < 256) ? dWih1[(size_t)(g0 * 256 + un0) * 256 + k] : dWhh1[(size_t)(g0 * 256 + un0) * 256 + k - 256];
            wreg[32 + e] = (k < 256) ? dWih1[(size_t)(g1 * 256 + un1) * 256 + k] : dWhh1[(size_t)(g1 * 256 + un1) * 256 + k - 256];
        }
        if (tid < 128) creg = C1[(size_t)(tid & 15) * 256 + bb * 8 + (tid >> 4)];
    }

    for (int t = 0; t < TT; t++) {
        int r = t & 1, w = r ^ 1;
        int* S  = DSL + (size_t)t * DSTEP;
        int* S1 = DSL + (size_t)(t - 1) * DSTEP;
        int* S2 = DSL + (size_t)(t - 2) * DSTEP;

        if (blk < 32) {                       // ---- A: cell0
            if (t >= 1) slot_wait(S1 + SA_O, 32, tid);
            if (t >= 2) slot_wait(S2 + SG_O, 1, tid);
            for (int b = 0; b < 16; b++) {
                int tok = (t == 0) ? 1 : tgt[b * TT + t - 1];
                if ((unsigned)tok >= VV) tok = 0;
                for (int k = tid; k < 384; k += 256) {
                    float v = (k < 128) ? emb[(size_t)tok * 128 + k] : H0[(size_t)r * 4096 + b * 256 + (k - 128)];
                    smem[b * 448 + (k / 24) * 28 + (k % 24)] = v;
                }
            }
            __syncthreads();
            {
                int q = tid & 15;
                float pa0[16], pa1[16];
                for (int b = 0; b < 16; b++) {
                    const float4* hv = (const float4*)&smem[b * 448 + q * 28];
                    float a0 = 0.f, a1 = 0.f;
#pragma unroll
                    for (int j = 0; j < 6; j++) {
                        float4 h4 = hv[j];
                        a0 += wreg[4 * j] * h4.x + wreg[4 * j + 1] * h4.y + wreg[4 * j + 2] * h4.z + wreg[4 * j + 3] * h4.w;
                        a1 += wreg[24 + 4 * j] * h4.x + wreg[25 + 4 * j] * h4.y + wreg[26 + 4 * j] * h4.z + wreg[27 + 4 * j] * h4.w;
                    }
                    pa0[b] = a0; pa1[b] = a1;
                }
#pragma unroll
                for (int m = 1; m < 16; m <<= 1) {
#pragma unroll
                    for (int b = 0; b < 16; b++) {
                        pa0[b] += __shfl_xor(pa0[b], m, 64);
                        pa1[b] += __shfl_xor(pa1[b], m, 64);
                    }
                }
                if (q == 0) {
                    int rp = tid >> 4;
#pragma unroll
                    for (int b = 0; b < 16; b++) {
                        smem[7168 + (rp * 2) * 17 + b] = pa0[b];
                        smem[7168 + (rp * 2 + 1) * 17 + b] = pa1[b];
                    }
                }
            }
            __syncthreads();
            if (tid < 128) {
                int ul = tid >> 4, b = tid & 15;
                int unit = blk * 8 + ul;
                float ai = smem[7168 + (ul * 4 + 0) * 17 + b] + db0[0 * 256 + unit];
                float af = smem[7168 + (ul * 4 + 1) * 17 + b] + db0[1 * 256 + unit];
                float ag = smem[7168 + (ul * 4 + 2) * 17 + b] + db0[2 * 256 + unit];
                float ao = smem[7168 + (ul * 4 + 3) * 17 + b] + db0[3 * 256 + unit];
                float c = sigf(af) * creg + sigf(ai) * fast_tanh(ag);
                float h = sigf(ao) * fast_tanh(c);
                creg = c;
                H0[(size_t)w * 4096 + b * 256 + unit] = h;
            }
            slot_signal(S + SA_O, blk);
        } else if (blk < 64) {                // ---- B: cell1
            int bb = blk - 32;
            slot_wait(S + SA_O, 32, tid);
            if (t >= 1) slot_wait(S1 + SB_O, 32, tid);
            if (t >= 2) slot_wait(S2 + SG_O, 1, tid);
            for (int b = 0; b < 16; b++) {
                for (int k = tid; k < 512; k += 256) {
                    float v = (k < 256) ? H0[(size_t)w * 4096 + b * 256 + k] : H1[(size_t)r * 4096 + b * 256 + (k - 256)];
                    smem[b * 576 + (k >> 5) * 36 + (k & 31)] = v;
                }
            }
            __syncthreads();
            {
                int q = tid & 15;
                float pa0[16], pa1[16];
                for (int b = 0; b < 16; b++) {
                    const float4* hv = (const float4*)&smem[b * 576 + q * 36];
                    float a0 = 0.f, a1 = 0.f;
#pragma unroll
                    for (int j = 0; j < 8; j++) {
                        float4 h4 = hv[j];
                        a0 += wreg[4 * j] * h4.x + wreg[4 * j + 1] * h4.y + wreg[4 * j + 2] * h4.z + wreg[4 * j + 3] * h4.w;
                        a1 += wreg[32 + 4 * j] * h4.x + wreg[33 + 4 * j] * h4.y + wreg[34 + 4 * j] * h4.z + wreg[35 + 4 * j] * h4.w;
                    }
                    pa0[b] = a0; pa1[b] = a1;
                }
#pragma unroll
                for (int m = 1; m < 16; m <<= 1) {
#pragma unroll
                    for (int b = 0; b < 16; b++) {
                        pa0[b] += __shfl_xor(pa0[b], m, 64);
                        pa1[b] += __shfl_xor(pa1[b], m, 64);
                    }
                }
                if (q == 0) {
                    int rp = tid >> 4;
#pragma unroll
                    for (int b = 0; b < 16; b++) {
                        smem[9216 + (rp * 2) * 17 + b] = pa0[b];
                        smem[9216 + (rp * 2 + 1) * 17 + b] = pa1[b];
                    }
                }
            }
            __syncthreads();
            if (tid < 128) {
                int ul = tid >> 4, b = tid & 15;
                int unit = bb * 8 + ul;
                float ai = smem[9216 + (ul * 4 + 0) * 17 + b] + db1[0 * 256 + unit];
                float af = smem[9216 + (ul * 4 + 1) * 17 + b] + db1[1 * 256 + unit];
                float ag = smem[9216 + (ul * 4 + 2) * 17 + b] + db1[2 * 256 + unit];
                float ao = smem[9216 + (ul * 4 + 3) * 17 + b] + db1[3 * 256 + unit];
                float c = sigf(af) * creg + sigf(ai) * fast_tanh(ag);
                float h = sigf(ao) * fast_tanh(c);
                creg = c;
                H1[(size_t)w * 4096 + b * 256 + unit] = h;
            }
            slot_signal(S + SB_O, bb);
        } else if (blk < 80) {                // ---- C: attn scores/softmax/cov/pcopy
            int b = blk - 64;
            slot_wait(S + SB_O, 32, tid);
            if (t >= 1) { slot_wait(S1 + SD_O, 64, tid); slot_wait(S1 + SG_O, 1, tid); }
            float* sh1 = smem; float* sda = smem + 256; float* ssc = smem + 512; float* red = smem + 912;
            sh1[tid] = H1[(size_t)w * 4096 + b * 256 + tid];
            __syncthreads();
            {
                float a = 0.f;
                const float4* wr = (const float4*)(Wda + (size_t)tid * 256);
                const float4* h4 = (const float4*)sh1;
                for (int k4 = 0; k4 < 64; k4++) {
                    float4 ww = wr[k4], x = h4[k4];
                    a += ww.x * x.x + ww.y * x.y + ww.z * x.z + ww.w * x.w;
                }
                sda[tid] = a;
            }
            __syncthreads();
            int lane = tid & 63, wv = tid >> 6;
            for (int tt = wv; tt < TIN; tt += 4) {
                float cvv = COVG[b * TIN + tt];
                const float* ea = ENCAT + ((size_t)b * TIN + tt) * 256;
                float s4 = 0.f;
#pragma unroll
                for (int j = 0; j < 4; j++) {
                    int c = lane + 64 * j;
                    float x = ea[c] + sda[c] + cvv * wcov[c];
                    s4 += vat[c] * fast_tanh(x);
                }
#pragma unroll
                for (int o = 32; o > 0; o >>= 1) s4 += __shfl_xor(s4, o, 64);
                if (lane == 0) ssc[tt] = (ids[b * TIN + tt] == 3) ? -1e30f : s4;
            }
            __syncthreads();
            float m = -1e30f;
            for (int i = tid; i < TIN; i += 256) m = fmaxf(m, ssc[i]);
            red[tid] = m; __syncthreads();
            for (int o = 128; o > 0; o >>= 1) { if (tid < o) red[tid] = fmaxf(red[tid], red[tid + o]); __syncthreads(); }
            m = red[0]; __syncthreads();
            float ps = 0.f;
            for (int i = tid; i < TIN; i += 256) { float e = __expf(ssc[i] - m); ssc[i] = e; ps += e; }
            red[tid] = ps; __syncthreads();
            for (int o = 128; o > 0; o >>= 1) { if (tid < o) red[tid] += red[tid + o]; __syncthreads(); }
            float inv = 1.f / red[0];
            __syncthreads();
            int tgb = tgt[b * TT + t];
            float pc = 0.f, ca = 0.f;
            for (int i = tid; i < TIN; i += 256) {
                float at = ssc[i] * inv;
                float cv = COVG[b * TIN + i];
                ca += fminf(at, cv);
                COVG[b * TIN + i] = cv + at;
                ATT[b * TIN + i] = at;
                if (ids[b * TIN + i] == tgb) pc += at;
            }
            red[tid] = pc; __syncthreads();
            for (int o = 128; o > 0; o >>= 1) { if (tid < o) red[tid] += red[tid + o]; __syncthreads(); }
            if (tid == 0) PCOPY[b] = red[0];
            __syncthreads();
            red[tid] = ca; __syncthreads();
            for (int o = 128; o > 0; o >>= 1) { if (tid < o) red[tid] += red[tid + o]; __syncthreads(); }
            if (tid == 0 && t < tlen[b]) COVL[b] += red[0];
            slot_signal(S + SC_O, b);
        } else if (blk < 144) {               // ---- D: ctx einsum
            int idx = blk - 80;
            int b = idx >> 2, dq = idx & 3;
            slot_wait(S + SC_O, 16, tid);
            if (t >= 1) slot_wait(S1 + SG_O, 1, tid);
            for (int i = tid; i < TIN; i += 256) smem[i] = ATT[b * TIN + i];
            __syncthreads();
            {
                int dl = tid & 127, ih = tid >> 7;
                float acc = 0.f;
                const float* es = ENCS + (size_t)b * TIN * 512 + dq * 128 + dl;
                for (int i = ih * 200; i < ih * 200 + 200; i++)
                    acc += smem[i] * es[(size_t)i * 512];
                smem[400 + ih * 128 + dl] = acc;
            }
            __syncthreads();
            if (tid < 128)
                CTX[(size_t)b * 512 + dq * 128 + tid] = smem[400 + tid] + smem[400 + 128 + tid];
            slot_signal(S + SD_O, idx);
        } else if (blk < 176) {               // ---- E: fc1
            slot_wait(S + SD_O, 64, tid);
            for (int i = tid; i < 4096; i += 256) smem[(i >> 8) * 772 + (i & 255)] = H1[(size_t)w * 4096 + i];
            for (int i = tid; i < 8192; i += 256) smem[(i >> 9) * 772 + 256 + (i & 511)] = CTX[i];
            __syncthreads();
            {
                int b = tid & 15, cl = tid >> 4;
                int c = (blk - 144) * 16 + cl;
                float a = bv1[c];
                const float4* wr = (const float4*)(Wv1 + (size_t)c * 768);
                const float4* xr = (const float4*)&smem[b * 772];
                for (int k4 = 0; k4 < 192; k4++) {
                    float4 ww = wr[k4], x = xr[k4];
                    a += ww.x * x.x + ww.y * x.y + ww.z * x.z + ww.w * x.w;
                }
                FC1[(size_t)b * 512 + c] = fmaxf(a, 0.f);
            }
            slot_signal(S + SE_O, blk - 144);
        }

        // ---- F: vocab partial softmax (all 256 blocks)
        slot_wait(S + SFo_O - 512 + 512, 0, tid); // no-op keep structure
        slot_wait(S + SE_O, 32, tid);
        if (t >= 1) slot_wait(S1 + SG_O, 1, tid);
        for (int i = tid; i < 8192; i += 256) smem[i] = FC1[i];
        __syncthreads();
        {
            int vl = tid & 127, kh = tid >> 7;
            int v = blk * 125 + vl;
            bool valid = (vl < 125) && (v < NV);
            float acc[16];
#pragma unroll
            for (int b = 0; b < 16; b++) acc[b] = 0.f;
            if (valid) {
                const float4* wr = (const float4*)(Wv2 + (size_t)v * 512 + (size_t)kh * 256);
                for (int k4 = 0; k4 < 64; k4++) {
                    float4 ww = wr[k4];
                    int k = kh * 256 + k4 * 4;
#pragma unroll
                    for (int b = 0; b < 16; b++)
                        acc[b] += ww.x * smem[b * 512 + k] + ww.y * smem[b * 512 + k + 1] + ww.z * smem[b * 512 + k + 2] + ww.w * smem[b * 512 + k + 3];
                }
            }
            if (kh == 1) {
#pragma unroll
                for (int b = 0; b < 16; b++) smem[8192 + vl * 17 + b] = acc[b];
            }
            __syncthreads();
            if (kh == 0) {
                if (valid) {
                    float bias = bv2[v];
#pragma unroll
                    for (int b = 0; b < 16; b++) {
                        float lg = acc[b] + smem[8192 + vl * 17 + b] + bias;
                        if (tgt[b * TT + t] - 2 == v) LTGT[b] = lg;
                        acc[b] = __expf(lg);
                    }
                } else {
#pragma unroll
                    for (int b = 0; b < 16; b++) acc[b] = 0.f;
                }
            }
            __syncthreads();
            if (kh == 0) {
#pragma unroll
                for (int b = 0; b < 16; b++) smem[8192 + vl * 17 + b] = acc[b];
            }
            __syncthreads();
            {
                int b = tid >> 4, sl = tid & 15;
                float s = 0.f;
#pragma unroll
                for (int j = 0; j < 8; j++) s += smem[8192 + (sl + 16 * j) * 17 + b];
                smem[b * 512 + sl] = s;
            }
            __syncthreads();
            if (tid < 16) {
                float den = 0.f;
#pragma unroll
                for (int j = 0; j < 16; j++) den += smem[tid * 512 + j];
                VPART[(size_t)tid * 256 + blk] = den;
            }
        }
        slot_signal(S + SFo_O, blk);

        if (blk == 255) {                     // ---- G: finalize
            slot_wait(S + SFo_O, 256, tid);
            int lane = tid & 63, wv = tid >> 6;
            for (int bi = 0; bi < 4; bi++) {
                int b = wv * 4 + bi;
                float a = 0.f;
                const float* cx = CTX + (size_t)b * 512;
                for (int k = lane; k < 512; k += 64) a += cx[k] * wctx[k];
                const float* h1 = H1 + (size_t)w * 4096 + b * 256;
                for (int k = lane; k < 256; k += 64) a += h1[k] * wdec[k];
                int tok = (t == 0) ? 1 : tgt[b * TT + t - 1];
                if ((unsigned)tok >= VV) tok = 0;
                const float* e = emb + (size_t)tok * 128;
                for (int k = lane; k < 128; k += 64) a += e[k] * wemb[k];
#pragma unroll
                for (int o = 32; o > 0; o >>= 1) a += __shfl_xor(a, o, 64);
                if (lane == 0) smem[280 + b] = a;
            }
            {
                int b = tid >> 4, sl = tid & 15;
                float s = 0.f;
                for (int j = sl; j < 256; j += 16) s += VPART[(size_t)b * 256 + j];
                smem[b * 17 + sl] = s;
            }
            __syncthreads();
            if (tid < 16) {
                int b = tid;
                float den = 0.f;
#pragma unroll
                for (int j = 0; j < 16; j++) den += smem[b * 17 + j];
                float pg = 1.f / (1.f + __expf(-(smem[280 + b] + bctx[0])));
                int tg = tgt[b * TT + t];
                float pv = (tg >= 2) ? (__expf(LTGT[b]) / den) : 0.f;
                float p = pg * pv + (1.f - pg) * PCOPY[b];
                if (t < tlen[b]) nllreg += -logf(p + 1e-9f);
                if (t == TT - 1) smem[300 + b] = nllreg;
            }
            if (t == TT - 1) {
                __syncthreads();
                if (tid == 0) {
                    float sn = 0.f, sc = 0.f;
                    for (int b = 0; b < 16; b++) { sn += smem[300 + b]; sc += COVL[b]; }
                    out[0] = sn; out[1] = sc; out[2] = sn + sc;
                }
            }
            slot_signal(S + SG_O, 0);
        }
    }
}

// ================================================================ host
extern "C" void kernel_launch(void* const* d_in, const int* in_sizes, int n_in,
                              void* d_out, int out_size, void* d_ws, size_t ws_size,
                              hipStream_t stream) {
    (void)in_sizes; (void)n_in; (void)out_size; (void)ws_size;
    const int*   ids   = (const int*)d_in[0];
    const int*   tgt   = (const int*)d_in[1];
    const int*   tlen  = (const int*)d_in[3];
    const float* emb   = (const float*)d_in[4];
    const float* eWih0 = (const float*)d_in[5];
    const float* eWhh0 = (const float*)d_in[6];
    const float* eb0   = (const float*)d_in[7];
    const float* eWih1 = (const float*)d_in[8];
    const float* eWhh1 = (const float*)d_in[9];
    const float* eb1   = (const float*)d_in[10];
    const float* We2dh = (const float*)d_in[11];
    const float* be2dh = (const float*)d_in[12];
    const float* We2dc = (const float*)d_in[13];
    const float* be2dc = (const float*)d_in[14];
    const float* dWih0 = (const float*)d_in[15];
    const float* dWhh0 = (const float*)d_in[16];
    const float* db0   = (const float*)d_in[17];
    const float* dWih1 = (const float*)d_in[18];
    const float* dWhh1 = (const float*)d_in[19];
    const float* db1   = (const float*)d_in[20];
    const float* Wea   = (const float*)d_in[21];
    const float* bea   = (const float*)d_in[22];
    const float* Wda   = (const float*)d_in[23];
    const float* wcov  = (const float*)d_in[24];
    const float* vat   = (const float*)d_in[25];
    const float* Wv1   = (const float*)d_in[26];
    const float* bv1   = (const float*)d_in[27];
    const float* Wv2   = (const float*)d_in[28];
    const float* bv2   = (const float*)d_in[29];
    const float* wctx  = (const float*)d_in[30];
    const float* bctx  = (const float*)d_in[31];
    const float* wdec  = (const float*)d_in[32];
    const float* wemb  = (const float*)d_in[33];
    float* out = (float*)d_out;

    float* ws = (float*)d_ws;
    float* GX    = ws; ws += (size_t)2 * TIN * B * 1024;
    float* HSEQ  = ws; ws += (size_t)TIN * B * 512;
    float* ENCS  = ws; ws += (size_t)B * TIN * 512;
    float* ENCAT = ws; ws += (size_t)B * TIN * 256;
    float* HTS   = ws; ws += 2 * B * 512;
    float* CTS   = ws; ws += 2 * B * 512;
    float* H0    = ws; ws += 2 * B * 256;
    float* C0    = ws; ws += B * 256;
    float* H1    = ws; ws += 2 * B * 256;
    float* C1    = ws; ws += B * 256;
    float* CTX   = ws; ws += B * 512;
    float* FC1   = ws; ws += B * 512;
    float* PCOPY = ws; ws += B;
    float* VPART = ws; ws += (size_t)B * 256;
    float* LTGT  = ws; ws += B;
    float* ATT   = ws; ws += (size_t)B * TIN;
    // ---- zero region (contiguous) ----
    float* ZBASE = ws;
    float* EHBUF = ws; ws += 2 * 2 * B * 256;                 // 16384
    float* COVG  = ws; ws += B * TIN;                         // 6400
    float* COVL  = ws; ws += B;                               // 16
    float* ENCSL0f = ws; ws += (size_t)2 * TIN * 16 * 16;     // 204800
    float* ENCSL1f = ws; ws += (size_t)2 * TIN * 16 * 16;     // 204800
    float* DSLf    = ws; ws += (size_t)TT * DSTEP;            // 692800
    int zcount = (int)(ws - ZBASE);                           // 1,125,200

    int* ENCSL0 = (int*)ENCSL0f;
    int* ENCSL1 = (int*)ENCSL1f;
    int* DSL    = (int*)DSLf;

    k_zero<<<(zcount + 255) / 256, 256, 0, stream>>>(ZBASE, zcount);
    k_gx0<<<2 * TIN, 256, 0, stream>>>(ids, emb, eWih0, eb0, GX);
    k_enc_layer<<<32, 256, 0, stream>>>(GX, eWhh0, EHBUF, HSEQ, HTS, CTS, ENCSL0, 0);
    k_gx1<<<2 * TIN, 256, 0, stream>>>(HSEQ, eWih1, eb1, GX);
    k_zero<<<64, 256, 0, stream>>>(EHBUF, 2 * 2 * B * 256);
    k_enc_layer<<<32, 256, 0, stream>>>(GX, eWhh1, EHBUF, ENCS, HTS, CTS, ENCSL1, 1);
    k_encattn<<<B * TIN, 256, 0, stream>>>(ENCS, Wea, bea, ENCAT);
    k_dec_init<<<32, 256, 0, stream>>>(HTS, CTS, We2dh, be2dh, We2dc, be2dc, H0, C0, H1, C1);
    k_decoder<<<256, 256, 0, stream>>>(ids, tgt, tlen, emb,
                                       dWih0, dWhh0, db0, dWih1, dWhh1, db1,
                                       Wda, wcov, vat, Wv1, bv1, Wv2, bv2,
                                       wctx, bctx, wdec, wemb,
                                       ENCS, ENCAT, ATT, COVG, COVL, CTX, FC1,
                                       PCOPY, VPART, LTGT, H0, C0, H1, C1, DSL, out);
}

// Round 3
// 31222.620 us; speedup vs baseline: 3.6128x; 3.6128x over previous
//
#include <hip/hip_runtime.h>
#include <hip/hip_bf16.h>

// Problem constants
#define B    16
#define TIN  400
#define TT   100
#define EMBD 128
#define EHD  256
#define VV   32000
#define NV   31998
// tokens: UNK=0, START=1, END=2, PAD=3

__device__ __forceinline__ float sigf(float x) { return 1.f / (1.f + __expf(-x)); }
__device__ __forceinline__ float fast_tanh(float x) {
    float e = __expf(2.f * x);
    return 1.f - 2.f / (e + 1.f);
}
__device__ __forceinline__ float bflo(unsigned u) { return __uint_as_float(u << 16); }
__device__ __forceinline__ float bfhi(unsigned u) { return __uint_as_float(u & 0xffff0000u); }

// ---- flag barrier helpers ----
__device__ __forceinline__ void slot_wait(int* sl, int n, int tid) {
    if (tid < n) {
        while (__hip_atomic_load(&sl[tid * 16], __ATOMIC_ACQUIRE, __HIP_MEMORY_SCOPE_AGENT) == 0)
            __builtin_amdgcn_s_sleep(1);
    }
    __syncthreads();
}
__device__ __forceinline__ void slot_signal(int* sl, int idx) {
    __syncthreads();
    if (threadIdx.x == 0)
        __hip_atomic_store(&sl[idx * 16], 1, __ATOMIC_RELEASE, __HIP_MEMORY_SCOPE_AGENT);
}

// ---------------------------------------------------------------- zero
__global__ __launch_bounds__(256) void k_zero(float* __restrict__ p, int n) {
    int i = blockIdx.x * 256 + threadIdx.x;
    if (i < n) p[i] = 0.f;
}

// ---------------------------------------------------------------- fp32 -> bf16 (RNE)
__global__ __launch_bounds__(256) void k_cvt(const float* __restrict__ src, unsigned short* __restrict__ dst, int n) {
    int i = blockIdx.x * 256 + threadIdx.x;
    if (i < n) {
        unsigned u = __float_as_uint(src[i]);
        unsigned r = (u + 0x7fffu + ((u >> 16) & 1u)) >> 16;
        dst[i] = (unsigned short)r;
    }
}

// ------------------------------------------------ encoder input GEMM L0
__global__ __launch_bounds__(256) void k_gx0(const int* __restrict__ ids, const float* __restrict__ emb,
                                             const float* __restrict__ Wih, const float* __restrict__ bias,
                                             float* __restrict__ gx) {
    int blk = blockIdx.x, dir = blk / TIN, t = blk % TIN;
    __shared__ float se[16][132];
    int tid = threadIdx.x;
    for (int i = tid; i < 16 * 128; i += 256) {
        int b = i >> 7, k = i & 127;
        int id = ids[b * TIN + t];
        if ((unsigned)id >= VV) id = 0;
        se[b][k] = emb[(size_t)id * EMBD + k];
    }
    __syncthreads();
    const float* W = Wih + (size_t)dir * 1024 * EMBD;
    const float* bb = bias + (size_t)dir * 1024;
    float* out = gx + ((size_t)dir * TIN + t) * (B * 1024);
    for (int c = tid; c < 1024; c += 256) {
        float acc[16];
#pragma unroll
        for (int b = 0; b < 16; b++) acc[b] = 0.f;
        const float4* wr = (const float4*)(W + (size_t)c * EMBD);
        for (int k4 = 0; k4 < 32; k4++) {
            float4 w = wr[k4];
            int k = k4 * 4;
#pragma unroll
            for (int b = 0; b < 16; b++)
                acc[b] += w.x * se[b][k] + w.y * se[b][k + 1] + w.z * se[b][k + 2] + w.w * se[b][k + 3];
        }
        float bv = bb[c];
#pragma unroll
        for (int b = 0; b < 16; b++) out[(size_t)b * 1024 + c] = acc[b] + bv;
    }
}

// ------------------------------------------------ encoder input GEMM L1
__global__ __launch_bounds__(256) void k_gx1(const float* __restrict__ hseq, const float* __restrict__ Wih,
                                             const float* __restrict__ bias, float* __restrict__ gx) {
    int blk = blockIdx.x, dir = blk / TIN, t = blk % TIN;
    __shared__ float sx[16][516];
    int tid = threadIdx.x;
    for (int i = tid; i < 16 * 512; i += 256) sx[i >> 9][i & 511] = hseq[(size_t)t * B * 512 + i];
    __syncthreads();
    const float* W = Wih + (size_t)dir * 1024 * 512;
    const float* bb = bias + (size_t)dir * 1024;
    float* out = gx + ((size_t)dir * TIN + t) * (B * 1024);
    for (int c = tid; c < 1024; c += 256) {
        float acc[16];
#pragma unroll
        for (int b = 0; b < 16; b++) acc[b] = 0.f;
        const float4* wr = (const float4*)(W + (size_t)c * 512);
        for (int k4 = 0; k4 < 128; k4++) {
            float4 w = wr[k4];
            int k = k4 * 4;
#pragma unroll
            for (int b = 0; b < 16; b++)
                acc[b] += w.x * sx[b][k] + w.y * sx[b][k + 1] + w.z * sx[b][k + 2] + w.w * sx[b][k + 3];
        }
        float bv = bb[c];
#pragma unroll
        for (int b = 0; b < 16; b++) out[(size_t)b * 1024 + c] = acc[b] + bv;
    }
}

// ------------------------------------------------ persistent encoder layer (verified R2)
__global__ __launch_bounds__(256) void k_enc_layer(const float* __restrict__ gx, const float* __restrict__ Whh,
                                                   float* __restrict__ hbuf, float* __restrict__ hout,
                                                   float* __restrict__ hTs, float* __restrict__ cTs,
                                                   int* __restrict__ slots, int layer) {
    int blk = blockIdx.x;
    int dir = blk >> 4;
    int ublk = blk & 15;
    int tid = threadIdx.x;
    int rp = tid >> 3, q = tid & 7;
    int lr0 = rp * 2, lr1 = lr0 + 1;
    int g0 = lr0 & 3, g1 = lr1 & 3;
    int unit0 = ublk * 16 + (lr0 >> 2);
    int unit1 = ublk * 16 + (lr1 >> 2);
    const float* Wd = Whh + (size_t)dir * 1024 * 256;
    float wreg[64];
    {
        const float* r0 = Wd + (size_t)(g0 * 256 + unit0) * 256 + q * 32;
        const float* r1 = Wd + (size_t)(g1 * 256 + unit1) * 256 + q * 32;
#pragma unroll
        for (int e = 0; e < 32; e++) { wreg[e] = r0[e]; wreg[32 + e] = r1[e]; }
    }
    int ub = tid >> 4, bb = tid & 15;
    float creg = 0.f;
    __shared__ float sh[16 * 288];
    __shared__ float sums[32 * 17];
    __shared__ float sums2[32 * 17];
    int* dirslots = slots + (size_t)dir * TIN * 16 * 16;

    for (int s = 0; s < TIN; s++) {
        int t = dir ? (TIN - 1 - s) : s;
        int par = s & 1;
        const float4* hp = (const float4*)(hbuf + ((size_t)par * 2 + dir) * B * 256);
        for (int i = tid; i < 1024; i += 256) {
            float4 v = hp[i];
            int b = i >> 6, k = (i & 63) * 4;
            *(float4*)&sh[b * 288 + (k >> 5) * 36 + (k & 31)] = v;
        }
        __syncthreads();
        float pa0[16], pa1[16];
        for (int b = 0; b < 16; b++) {
            const float4* hv = (const float4*)&sh[b * 288 + q * 36];
            float a0 = 0.f, a1 = 0.f;
#pragma unroll
            for (int j = 0; j < 8; j++) {
                float4 h4 = hv[j];
                a0 += wreg[4 * j] * h4.x + wreg[4 * j + 1] * h4.y + wreg[4 * j + 2] * h4.z + wreg[4 * j + 3] * h4.w;
                a1 += wreg[32 + 4 * j] * h4.x + wreg[33 + 4 * j] * h4.y + wreg[34 + 4 * j] * h4.z + wreg[35 + 4 * j] * h4.w;
            }
            pa0[b] = a0; pa1[b] = a1;
        }
#pragma unroll
        for (int m = 1; m < 8; m <<= 1) {
#pragma unroll
            for (int b = 0; b < 16; b++) {
                pa0[b] += __shfl_xor(pa0[b], m, 64);
                pa1[b] += __shfl_xor(pa1[b], m, 64);
            }
        }
        if (q == 0) {
            float* s0 = (lr0 < 32) ? sums : sums2;
            float* s1 = (lr1 < 32) ? sums : sums2;
            int l0 = lr0 & 31, l1 = lr1 & 31;
#pragma unroll
            for (int b = 0; b < 16; b++) { s0[l0 * 17 + b] = pa0[b]; s1[l1 * 17 + b] = pa1[b]; }
        }
        __syncthreads();
        {
            int unit = ublk * 16 + ub;
            const float* gp = gx + (((size_t)dir * TIN + t) * B + bb) * 1024;
            int lri = ub * 4;
            float ai = ((lri + 0 < 32) ? sums[(lri + 0) * 17 + bb] : sums2[((lri + 0) & 31) * 17 + bb]) + gp[0 * 256 + unit];
            float af = ((lri + 1 < 32) ? sums[(lri + 1) * 17 + bb] : sums2[((lri + 1) & 31) * 17 + bb]) + gp[1 * 256 + unit];
            float ag = ((lri + 2 < 32) ? sums[(lri + 2) * 17 + bb] : sums2[((lri + 2) & 31) * 17 + bb]) + gp[2 * 256 + unit];
            float ao = ((lri + 3 < 32) ? sums[(lri + 3) * 17 + bb] : sums2[((lri + 3) & 31) * 17 + bb]) + gp[3 * 256 + unit];
            float c = sigf(af) * creg + sigf(ai) * fast_tanh(ag);
            float h = sigf(ao) * fast_tanh(c);
            creg = c;
            hbuf[((size_t)(par ^ 1) * 2 + dir) * B * 256 + (size_t)bb * 256 + unit] = h;
            if (layer == 0) hout[((size_t)t * B + bb) * 512 + dir * 256 + unit] = h;
            else            hout[((size_t)bb * TIN + t) * 512 + dir * 256 + unit] = h;
            if (s == TIN - 1) {
                hTs[((size_t)layer * B + bb) * 512 + dir * 256 + unit] = h;
                cTs[((size_t)layer * B + bb) * 512 + dir * 256 + unit] = c;
            }
        }
        int* sl = dirslots + (size_t)s * 16 * 16;
        slot_signal(sl, ublk);
        slot_wait(sl, 16, tid);
    }
}

// ------------------------------------------------ enc_attn precompute
__global__ __launch_bounds__(256) void k_encattn(const float* __restrict__ encs, const float* __restrict__ Wea,
                                                 const float* __restrict__ bea, float* __restrict__ encat) {
    int blk = blockIdx.x;
    __shared__ float sx[512];
    int tid = threadIdx.x;
    const float* row = encs + (size_t)blk * 512;
    for (int i = tid; i < 512; i += 256) sx[i] = row[i];
    __syncthreads();
    float a = bea[tid];
    const float4* wr = (const float4*)(Wea + (size_t)tid * 512);
    const float4* xr = (const float4*)sx;
    for (int k4 = 0; k4 < 128; k4++) {
        float4 w = wr[k4], x = xr[k4];
        a += w.x * x.x + w.y * x.y + w.z * x.z + w.w * x.w;
    }
    encat[(size_t)blk * 256 + tid] = a;
}

// ------------------------------------------------ decoder init
__global__ __launch_bounds__(256) void k_dec_init(const float* __restrict__ hTs, const float* __restrict__ cTs,
                                                  const float* __restrict__ Wh, const float* __restrict__ bh,
                                                  const float* __restrict__ Wc, const float* __restrict__ bc,
                                                  float* __restrict__ h0buf, float* __restrict__ c0,
                                                  float* __restrict__ h1buf, float* __restrict__ c1) {
    int idx = blockIdx.x * 256 + threadIdx.x;
    int l = idx >> 12, b = (idx >> 8) & 15, d = idx & 255;
    const float4* h4 = (const float4*)(hTs + ((size_t)l * B + b) * 512);
    const float4* c4 = (const float4*)(cTs + ((size_t)l * B + b) * 512);
    const float4* wh4 = (const float4*)(Wh + (size_t)d * 512);
    const float4* wc4 = (const float4*)(Wc + (size_t)d * 512);
    float ah = bh[d], ac = bc[d];
    for (int k4 = 0; k4 < 128; k4++) {
        float4 w = wh4[k4], x = h4[k4];
        ah += w.x * x.x + w.y * x.y + w.z * x.z + w.w * x.w;
        w = wc4[k4]; x = c4[k4];
        ac += w.x * x.x + w.y * x.y + w.z * x.z + w.w * x.w;
    }
    if (l == 0) { h0buf[(size_t)b * 256 + d] = ah; c0[(size_t)b * 256 + d] = ac; }
    else        { h1buf[(size_t)b * 256 + d] = ah; c1[(size_t)b * 256 + d] = ac; }
}

// ------------------------------------------------ decoder LSTM cell step (verified R1)
__global__ __launch_bounds__(256) void k_dec_cell(const int* __restrict__ tgt, const float* __restrict__ emb,
                                                  const float* __restrict__ xbuf, const float* __restrict__ Wih,
                                                  const float* __restrict__ Whh, const float* __restrict__ bias,
                                                  float* __restrict__ hpair, float* __restrict__ cst,
                                                  int t, int mode) {
    int tid = threadIdx.x;
    int b = tid & 15, u = tid >> 4;
    int unit = blockIdx.x * 16 + u;
    int r = t & 1, w = r ^ 1;
    __shared__ float sx[16][260];
    __shared__ float sh[16][260];
    if (mode == 0) {
        for (int i = tid; i < 16 * 128; i += 256) {
            int bb = i >> 7, k = i & 127;
            int tok = (t == 0) ? 1 : tgt[bb * TT + t - 1];
            if ((unsigned)tok >= VV) tok = 0;
            sx[bb][k] = emb[(size_t)tok * EMBD + k];
        }
    } else {
        for (int i = tid; i < 16 * 256; i += 256) sx[i >> 8][i & 255] = xbuf[i];
    }
    const float* hp = hpair + (size_t)r * B * 256;
    for (int i = tid; i < 16 * 256; i += 256) sh[i >> 8][i & 255] = hp[i];
    __syncthreads();
    float ai = bias[unit], af = bias[256 + unit], ag = bias[512 + unit], ao = bias[768 + unit];
    const int KX = mode ? 256 : 128;
    {
        const float4* xi = (const float4*)(Wih + (size_t)(0 * 256 + unit) * KX);
        const float4* xf = (const float4*)(Wih + (size_t)(1 * 256 + unit) * KX);
        const float4* xg = (const float4*)(Wih + (size_t)(2 * 256 + unit) * KX);
        const float4* xo = (const float4*)(Wih + (size_t)(3 * 256 + unit) * KX);
        const float4* xv = (const float4*)&sx[b][0];
        int n4 = KX >> 2;
        for (int k4 = 0; k4 < n4; k4++) {
            float4 x = xv[k4];
            float4 w;
            w = xi[k4]; ai += w.x * x.x + w.y * x.y + w.z * x.z + w.w * x.w;
            w = xf[k4]; af += w.x * x.x + w.y * x.y + w.z * x.z + w.w * x.w;
            w = xg[k4]; ag += w.x * x.x + w.y * x.y + w.z * x.z + w.w * x.w;
            w = xo[k4]; ao += w.x * x.x + w.y * x.y + w.z * x.z + w.w * x.w;
        }
    }
    {
        const float4* wi = (const float4*)(Whh + (size_t)(0 * 256 + unit) * 256);
        const float4* wf = (const float4*)(Whh + (size_t)(1 * 256 + unit) * 256);
        const float4* wg = (const float4*)(Whh + (size_t)(2 * 256 + unit) * 256);
        const float4* wo = (const float4*)(Whh + (size_t)(3 * 256 + unit) * 256);
        const float4* hv4 = (const float4*)&sh[b][0];
        for (int k4 = 0; k4 < 64; k4++) {
            float4 h = hv4[k4];
            float4 w;
            w = wi[k4]; ai += w.x * h.x + w.y * h.y + w.z * h.z + w.w * h.w;
            w = wf[k4]; af += w.x * h.x + w.y * h.y + w.z * h.z + w.w * h.w;
            w = wg[k4]; ag += w.x * h.x + w.y * h.y + w.z * h.z + w.w * h.w;
            w = wo[k4]; ao += w.x * h.x + w.y * h.y + w.z * h.z + w.w * h.w;
        }
    }
    float* cp = cst + (size_t)b * 256 + unit;
    float c = *cp;
    c = sigf(af) * c + sigf(ai) * fast_tanh(ag);
    float h = sigf(ao) * fast_tanh(c);
    *cp = c;
    hpair[(size_t)w * B * 256 + (size_t)b * 256 + unit] = h;
}

// ------------------------------------------------ attention + ctx (one block per b)
__global__ __launch_bounds__(256) void k_attn(const int* __restrict__ ids, const int* __restrict__ tgt,
                                              const int* __restrict__ tlen, const float* __restrict__ encat,
                                              const float* __restrict__ encs, const float* __restrict__ Wda,
                                              const float* __restrict__ wcov, const float* __restrict__ vat,
                                              const float* __restrict__ h1buf, float* __restrict__ coverage,
                                              float* __restrict__ ctx, float* __restrict__ pcopy,
                                              float* __restrict__ cov, int t) {
    int b = blockIdx.x;
    int tid = threadIdx.x;
    int w = (t & 1) ^ 1;
    __shared__ float sh1[256];
    __shared__ float sda[256];
    __shared__ float ssc[TIN];
    __shared__ float red[256];
    __shared__ float sred[2048];
    sh1[tid] = h1buf[(size_t)w * B * 256 + (size_t)b * 256 + tid];
    __syncthreads();
    {
        float a = 0.f;
        const float4* wr = (const float4*)(Wda + (size_t)tid * 256);
        const float4* h4 = (const float4*)sh1;
        for (int k4 = 0; k4 < 64; k4++) {
            float4 ww = wr[k4], x = h4[k4];
            a += ww.x * x.x + ww.y * x.y + ww.z * x.z + ww.w * x.w;
        }
        sda[tid] = a;
    }
    __syncthreads();
    int lane = tid & 63, wv = tid >> 6;
    for (int tt = wv; tt < TIN; tt += 4) {
        float cvv = coverage[b * TIN + tt];
        const float* ea = encat + ((size_t)b * TIN + tt) * 256;
        float s4 = 0.f;
#pragma unroll
        for (int j = 0; j < 4; j++) {
            int c = lane + 64 * j;
            float x = ea[c] + sda[c] + cvv * wcov[c];
            s4 += vat[c] * fast_tanh(x);
        }
#pragma unroll
        for (int o = 32; o > 0; o >>= 1) s4 += __shfl_xor(s4, o, 64);
        if (lane == 0) ssc[tt] = (ids[b * TIN + tt] == 3) ? -1e30f : s4;
    }
    __syncthreads();
    // softmax over 400
    float m = -1e30f;
    for (int i = tid; i < TIN; i += 256) m = fmaxf(m, ssc[i]);
    red[tid] = m; __syncthreads();
    for (int o = 128; o > 0; o >>= 1) { if (tid < o) red[tid] = fmaxf(red[tid], red[tid + o]); __syncthreads(); }
    m = red[0]; __syncthreads();
    float ps = 0.f;
    for (int i = tid; i < TIN; i += 256) { float e = __expf(ssc[i] - m); ssc[i] = e; ps += e; }
    red[tid] = ps; __syncthreads();
    for (int o = 128; o > 0; o >>= 1) { if (tid < o) red[tid] += red[tid + o]; __syncthreads(); }
    float inv = 1.f / red[0];
    __syncthreads();
    int tgb = tgt[b * TT + t];
    float pc = 0.f, ca = 0.f;
    for (int i = tid; i < TIN; i += 256) {
        float at = ssc[i] * inv; ssc[i] = at;
        float cv = coverage[b * TIN + i];
        ca += fminf(at, cv);
        coverage[b * TIN + i] = cv + at;
        if (ids[b * TIN + i] == tgb) pc += at;
    }
    red[tid] = pc; __syncthreads();
    for (int o = 128; o > 0; o >>= 1) { if (tid < o) red[tid] += red[tid + o]; __syncthreads(); }
    if (tid == 0) pcopy[b] = red[0];
    __syncthreads();
    red[tid] = ca; __syncthreads();
    for (int o = 128; o > 0; o >>= 1) { if (tid < o) red[tid] += red[tid + o]; __syncthreads(); }
    if (tid == 0 && t < tlen[b]) cov[b] += red[0];
    __syncthreads();
    // ctx = attn @ enc_states[b] : coalesced row streaming, per-wave partials
    {
        float acc[8];
#pragma unroll
        for (int j = 0; j < 8; j++) acc[j] = 0.f;
        for (int i = wv; i < TIN; i += 4) {
            float a = ssc[i];
            const float* es = encs + ((size_t)b * TIN + i) * 512;
#pragma unroll
            for (int j = 0; j < 8; j++) acc[j] += a * es[lane + 64 * j];
        }
#pragma unroll
        for (int j = 0; j < 8; j++) sred[wv * 512 + 64 * j + lane] = acc[j];
        __syncthreads();
        for (int d = tid; d < 512; d += 256)
            ctx[(size_t)b * 512 + d] = sred[d] + sred[512 + d] + sred[1024 + d] + sred[1536 + d];
    }
}

// ------------------------------------------------ fc1 = relu([h1,ctx] @ W_v1.T + b)
__global__ __launch_bounds__(256) void k_fc1(const float* __restrict__ h1buf, const float* __restrict__ ctxp,
                                             const float* __restrict__ W, const float* __restrict__ bias,
                                             float* __restrict__ fc1, int t) {
    __shared__ float sx[16][772];
    int tid = threadIdx.x;
    int w = (t & 1) ^ 1;
    for (int i = tid; i < 16 * 256; i += 256) sx[i >> 8][i & 255] = h1buf[(size_t)w * B * 256 + i];
    for (int i = tid; i < 16 * 512; i += 256) sx[i >> 9][256 + (i & 511)] = ctxp[i];
    __syncthreads();
    int b = tid & 15, cl = tid >> 4;
    int c = blockIdx.x * 16 + cl;
    float a = bias[c];
    const float4* wr = (const float4*)(W + (size_t)c * 768);
    const float4* xr = (const float4*)&sx[b][0];
    for (int k4 = 0; k4 < 192; k4++) {
        float4 ww = wr[k4], x = xr[k4];
        a += ww.x * x.x + ww.y * x.y + ww.z * x.z + ww.w * x.w;
    }
    fc1[(size_t)b * 512 + c] = fmaxf(a, 0.f);
}

// ------------------------------------------------ vocab logits (bf16 weights) + partial exp-sums
__global__ __launch_bounds__(256) void k_vocab(const float* __restrict__ fc1, const unsigned short* __restrict__ W2b,
                                               const float* __restrict__ b2, const int* __restrict__ tgt,
                                               float* __restrict__ vpart, float* __restrict__ ltgt, int t) {
    __shared__ float sf[16][512];
    __shared__ float half_[128][17];
    int tid = threadIdx.x;
    for (int i = tid; i < 16 * 512; i += 256) sf[i >> 9][i & 511] = fc1[i];
    __syncthreads();
    int vl = tid & 127, kh = tid >> 7;
    int v = blockIdx.x * 128 + vl;
    float acc[16];
#pragma unroll
    for (int b = 0; b < 16; b++) acc[b] = 0.f;
    if (v < NV) {
        const uint4* wr = (const uint4*)(W2b + (size_t)v * 512 + (size_t)kh * 256);
        for (int k8 = 0; k8 < 32; k8++) {
            uint4 pw = wr[k8];
            int k = kh * 256 + k8 * 8;
            float w0 = bflo(pw.x), w1 = bfhi(pw.x);
            float w2 = bflo(pw.y), w3 = bfhi(pw.y);
            float w4 = bflo(pw.z), w5 = bfhi(pw.z);
            float w6 = bflo(pw.w), w7 = bfhi(pw.w);
#pragma unroll
            for (int b = 0; b < 16; b++) {
                const float* s = &sf[b][k];
                acc[b] += w0 * s[0] + w1 * s[1] + w2 * s[2] + w3 * s[3]
                        + w4 * s[4] + w5 * s[5] + w6 * s[6] + w7 * s[7];
            }
        }
    }
    if (kh == 1) {
#pragma unroll
        for (int b = 0; b < 16; b++) half_[vl][b] = acc[b];
    }
    __syncthreads();
    if (kh == 0) {
        if (v < NV) {
            float bias = b2[v];
#pragma unroll
            for (int b = 0; b < 16; b++) {
                float lg = acc[b] + half_[vl][b] + bias;
                if (tgt[b * TT + t] - 2 == v) ltgt[b] = lg;
                acc[b] = __expf(lg);
            }
        } else {
#pragma unroll
            for (int b = 0; b < 16; b++) acc[b] = 0.f;
        }
    }
    __syncthreads();
    if (kh == 0) {
#pragma unroll
        for (int b = 0; b < 16; b++) half_[vl][b] = acc[b];
    }
    __syncthreads();
    {
        int b = tid >> 4, sl = tid & 15;
        float s = 0.f;
#pragma unroll
        for (int j = 0; j < 8; j++) s += half_[sl + 16 * j][b];
        sf[b][sl] = s;
    }
    __syncthreads();
    if (tid < 16) {
        float den = 0.f;
#pragma unroll
        for (int j = 0; j < 16; j++) den += sf[tid][j];
        vpart[(size_t)tid * 250 + blockIdx.x] = den;
    }
}

// ------------------------------------------------ finalize step
__global__ __launch_bounds__(256) void k_final(const float* __restrict__ vpart, const float* __restrict__ ltgt,
                                               const float* __restrict__ pcopy, const float* __restrict__ ctxp,
                                               const float* __restrict__ h1buf, const int* __restrict__ tgt,
                                               const int* __restrict__ tlen, const float* __restrict__ emb,
                                               const float* __restrict__ wctx, const float* __restrict__ bctx,
                                               const float* __restrict__ wdec, const float* __restrict__ wemb,
                                               float* __restrict__ nll, const float* __restrict__ cov,
                                               float* __restrict__ out, int t) {
    int tid = threadIdx.x;
    int lane = tid & 63, wv = tid >> 6;
    int w = (t & 1) ^ 1;
    __shared__ float sgen[16];
    __shared__ float sden[16][17];
    for (int bi = 0; bi < 4; bi++) {
        int b = wv * 4 + bi;
        float a = 0.f;
        const float* cx = ctxp + (size_t)b * 512;
        for (int k = lane; k < 512; k += 64) a += cx[k] * wctx[k];
        const float* h1 = h1buf + (size_t)w * B * 256 + (size_t)b * 256;
        for (int k = lane; k < 256; k += 64) a += h1[k] * wdec[k];
        int tok = (t == 0) ? 1 : tgt[b * TT + t - 1];
        if ((unsigned)tok >= VV) tok = 0;
        const float* e = emb + (size_t)tok * EMBD;
        for (int k = lane; k < 128; k += 64) a += e[k] * wemb[k];
#pragma unroll
        for (int o = 32; o > 0; o >>= 1) a += __shfl_xor(a, o, 64);
        if (lane == 0) sgen[b] = a;
    }
    {
        int b = tid >> 4, sl = tid & 15;
        float s = 0.f;
        for (int j = sl; j < 250; j += 16) s += vpart[(size_t)b * 250 + j];
        sden[b][sl] = s;
    }
    __syncthreads();
    if (tid < 16) {
        int b = tid;
        float den = 0.f;
#pragma unroll
        for (int j = 0; j < 16; j++) den += sden[b][j];
        float pg = 1.f / (1.f + __expf(-(sgen[b] + bctx[0])));
        int tg = tgt[b * TT + t];
        float pv = (tg >= 2) ? (__expf(ltgt[b]) / den) : 0.f;
        float p = pg * pv + (1.f - pg) * pcopy[b];
        if (t < tlen[b]) nll[b] += -logf(p + 1e-9f);
    }
    if (t == TT - 1) {
        __syncthreads();
        if (tid == 0) {
            float sn = 0.f, sc = 0.f;
            for (int b = 0; b < 16; b++) { sn += nll[b]; sc += cov[b]; }
            out[0] = sn; out[1] = sc; out[2] = sn + sc;
        }
    }
}

// ================================================================ host
extern "C" void kernel_launch(void* const* d_in, const int* in_sizes, int n_in,
                              void* d_out, int out_size, void* d_ws, size_t ws_size,
                              hipStream_t stream) {
    (void)in_sizes; (void)n_in; (void)out_size; (void)ws_size;
    const int*   ids   = (const int*)d_in[0];
    const int*   tgt   = (const int*)d_in[1];
    const int*   tlen  = (const int*)d_in[3];
    const float* emb   = (const float*)d_in[4];
    const float* eWih0 = (const float*)d_in[5];
    const float* eWhh0 = (const float*)d_in[6];
    const float* eb0   = (const float*)d_in[7];
    const float* eWih1 = (const float*)d_in[8];
    const float* eWhh1 = (const float*)d_in[9];
    const float* eb1   = (const float*)d_in[10];
    const float* We2dh = (const float*)d_in[11];
    const float* be2dh = (const float*)d_in[12];
    const float* We2dc = (const float*)d_in[13];
    const float* be2dc = (const float*)d_in[14];
    const float* dWih0 = (const float*)d_in[15];
    const float* dWhh0 = (const float*)d_in[16];
    const float* db0   = (const float*)d_in[17];
    const float* dWih1 = (const float*)d_in[18];
    const float* dWhh1 = (const float*)d_in[19];
    const float* db1   = (const float*)d_in[20];
    const float* Wea   = (const float*)d_in[21];
    const float* bea   = (const float*)d_in[22];
    const float* Wda   = (const float*)d_in[23];
    const float* wcov  = (const float*)d_in[24];
    const float* vat   = (const float*)d_in[25];
    const float* Wv1   = (const float*)d_in[26];
    const float* bv1   = (const float*)d_in[27];
    const float* Wv2   = (const float*)d_in[28];
    const float* bv2   = (const float*)d_in[29];
    const float* wctx  = (const float*)d_in[30];
    const float* bctx  = (const float*)d_in[31];
    const float* wdec  = (const float*)d_in[32];
    const float* wemb  = (const float*)d_in[33];
    float* out = (float*)d_out;

    float* ws = (float*)d_ws;
    float* GX    = ws; ws += (size_t)2 * TIN * B * 1024;   // reused as bf16 Wv2 after encoder
    float* HSEQ  = ws; ws += (size_t)TIN * B * 512;
    float* ENCS  = ws; ws += (size_t)B * TIN * 512;
    float* ENCAT = ws; ws += (size_t)B * TIN * 256;
    float* HTS   = ws; ws += 2 * B * 512;
    float* CTS   = ws; ws += 2 * B * 512;
    float* H0    = ws; ws += 2 * B * 256;
    float* C0    = ws; ws += B * 256;
    float* H1    = ws; ws += 2 * B * 256;
    float* C1    = ws; ws += B * 256;
    float* CTX   = ws; ws += B * 512;
    float* FC1   = ws; ws += B * 512;
    float* PCOPY = ws; ws += B;
    float* VPART = ws; ws += (size_t)B * 250;
    float* LTGT  = ws; ws += B;
    // ---- zero region (contiguous) ----
    float* ZBASE = ws;
    float* EHBUF = ws; ws += 2 * 2 * B * 256;               // 16384
    float* COVG  = ws; ws += B * TIN;                       // 6400
    float* COVL  = ws; ws += B;                             // 16
    float* NLL   = ws; ws += B;                             // 16
    float* ENCSL0f = ws; ws += (size_t)2 * TIN * 16 * 16;   // 204800
    float* ENCSL1f = ws; ws += (size_t)2 * TIN * 16 * 16;   // 204800
    int zcount = (int)(ws - ZBASE);                         // 432,416

    int* ENCSL0 = (int*)ENCSL0f;
    int* ENCSL1 = (int*)ENCSL1f;
    unsigned short* WV2B = (unsigned short*)GX;

    k_zero<<<(zcount + 255) / 256, 256, 0, stream>>>(ZBASE, zcount);
    // ---- encoder (persistent per layer) ----
    k_gx0<<<2 * TIN, 256, 0, stream>>>(ids, emb, eWih0, eb0, GX);
    k_enc_layer<<<32, 256, 0, stream>>>(GX, eWhh0, EHBUF, HSEQ, HTS, CTS, ENCSL0, 0);
    k_gx1<<<2 * TIN, 256, 0, stream>>>(HSEQ, eWih1, eb1, GX);
    k_zero<<<64, 256, 0, stream>>>(EHBUF, 2 * 2 * B * 256);
    k_enc_layer<<<32, 256, 0, stream>>>(GX, eWhh1, EHBUF, ENCS, HTS, CTS, ENCSL1, 1);
    // ---- Wv2 -> bf16 (GX dead after encoder) ----
    {
        int n = NV * 512;
        k_cvt<<<(n + 255) / 256, 256, 0, stream>>>(Wv2, WV2B, n);
    }
    // ---- attention precompute + decoder init ----
    k_encattn<<<B * TIN, 256, 0, stream>>>(ENCS, Wea, bea, ENCAT);
    k_dec_init<<<32, 256, 0, stream>>>(HTS, CTS, We2dh, be2dh, We2dc, be2dc, H0, C0, H1, C1);
    // ---- decoder loop (per-step launches) ----
    for (int t = 0; t < TT; t++) {
        int w = (t & 1) ^ 1;
        k_dec_cell<<<16, 256, 0, stream>>>(tgt, emb, nullptr, dWih0, dWhh0, db0, H0, C0, t, 0);
        k_dec_cell<<<16, 256, 0, stream>>>(tgt, emb, H0 + (size_t)w * B * 256, dWih1, dWhh1, db1, H1, C1, t, 1);
        k_attn<<<B, 256, 0, stream>>>(ids, tgt, tlen, ENCAT, ENCS, Wda, wcov, vat, H1, COVG, CTX, PCOPY, COVL, t);
        k_fc1<<<32, 256, 0, stream>>>(H1, CTX, Wv1, bv1, FC1, t);
        k_vocab<<<250, 256, 0, stream>>>(FC1, WV2B, bv2, tgt, VPART, LTGT, t);
        k_final<<<1, 256, 0, stream>>>(VPART, LTGT, PCOPY, CTX, H1, tgt, tlen, emb,
                                       wctx, bctx, wdec, wemb, NLL, COVL, out, t);
    }
}